// Round 3
// baseline (576.549 us; speedup 1.0000x reference)
//
#include <hip/hip_runtime.h>
#include <hip/hip_bf16.h>

// GNN_65498251264428: 2-layer GraphConv + mean pool + Linear(64,1).
// N=100000 nodes, E=1000000 edges, F=H=64, G=128 graphs.
//
// Layer-2 algebraic collapse (layer 2 is linear):
//   out[g] = (u.T_g + v.S_g)/c_g + (w_lin.b2_rel + b_lin)
//   u = w2_rel^T w_lin, v = w2_root^T w_lin
//   S_g -> per-node scalar q_i = v.h1_i ; T_g -> per-edge w_e * p_{src}
//
// Round 12: R11's fp8 halved gather FETCH (104->47MB) and cut 66->46us, but
// Little's law says only ~18 lines in flight per CU -> MLP-bound, not BW.
// (a) gather: unroll-4 with clamped indices -> 4 independent row loads in
//     flight per 4-lane group, no divergent tail.
// (b) kill cvt8 launch: prep's cvt blocks write xh (bf16) AND xf8 (fp8)
//     straight from x (also single-rounding). xf8 gets its own ws region.
// (c) kill bucket_scan launch: bucket_fill and csr_build redo the 196-wide
//     prefix scan locally in LDS (cursor is zero-init via memset; final
//     position = local_boff + atomic rank).
// (d) S-pool folded into gather epilogue (atomicAdd gq[batch[node]]); graph
//     node-counts via batch-hist blocks in prep. pool = T-term only.
// memset + 5 kernels (was memset + 7).

#define N_NODES 100000
#define N_EDGES 1000000
#define NGRAPHS 128
#define BN 512                              // nodes per bucket
#define NBUCK ((N_NODES + BN - 1) / BN)     // 196
#define FILL_T 16                           // edges per thread in bucket_fill
#define FILL_TILE (256 * FILL_T)            // 4096
#define FILL_NB ((N_EDGES + FILL_TILE - 1) / FILL_TILE)  // 245
#define NTILES (N_NODES / 16)               // 6250 (exact)
#define AST 72                              // LDS row stride in shorts (144B: 16B-aligned frags)

#define PREP_CVT_NB 3125                    // 800000/256 exact
#define HIST0 (PREP_CVT_NB + 1)             // 3126
#define HIST_NB 256
#define CNT0 (HIST0 + HIST_NB)              // 3382
#define CNT_NB 64
#define PREP_TOTAL (CNT0 + CNT_NB)          // 3446

typedef __attribute__((ext_vector_type(8))) short bf16x8;
typedef __attribute__((ext_vector_type(8))) unsigned short u16x8;
typedef __attribute__((ext_vector_type(4))) float f32x4;
typedef __attribute__((ext_vector_type(2))) float f32x2;

__device__ __forceinline__ unsigned short f2bf(float f) {
    unsigned u = __float_as_uint(f);
    unsigned r = (u + 0x7FFFu + ((u >> 16) & 1u)) >> 16;  // RNE
    return (unsigned short)r;
}
__device__ __forceinline__ float bf2f(unsigned short h) {
    return __uint_as_float(((unsigned)h) << 16);
}
// 4 fp8 (one dword) -> f32 via HW cvt, FMA into a[0..3]
__device__ __forceinline__ void fma4(int w, float wt, float* a) {
    f32x2 lo = __builtin_amdgcn_cvt_pk_f32_fp8(w, false);
    f32x2 hi = __builtin_amdgcn_cvt_pk_f32_fp8(w, true);
    a[0] += wt * lo[0];
    a[1] += wt * lo[1];
    a[2] += wt * hi[0];
    a[3] += wt * hi[1];
}
__device__ __forceinline__ int pack4(float f0, float f1, float f2, float f3) {
    int w = __builtin_amdgcn_cvt_pk_fp8_f32(f0, f1, 0, false);
    w = __builtin_amdgcn_cvt_pk_fp8_f32(f2, f3, w, true);
    return w;
}

// ---- kernel 0: fused x->{bf16,fp8} cvt + weight prep + dst hist + batch cnt
__global__ __launch_bounds__(256) void prep_all_kernel(
    const float* __restrict__ x, unsigned short* __restrict__ xh,
    int* __restrict__ xf8,
    const float* __restrict__ w1rel, const float* __restrict__ w1root,
    const float* __restrict__ w2rel, const float* __restrict__ w2root,
    const float* __restrict__ wlin, const float* __restrict__ b2rel,
    const float* __restrict__ blin, unsigned short* __restrict__ whirel,
    unsigned short* __restrict__ wlorel, unsigned short* __restrict__ whiroot,
    unsigned short* __restrict__ wloroot, float* __restrict__ u,
    float* __restrict__ v, float* __restrict__ C,
    const int* __restrict__ ei, int* __restrict__ bcount,
    const int* __restrict__ batch, float* __restrict__ gc, int E) {
    int tid = threadIdx.x;
    if (blockIdx.x < PREP_CVT_NB) {  // cvt part: 8 floats/thread
        int i = blockIdx.x * 256 + tid;
        const float4* xp = (const float4*)x + (size_t)i * 2;
        float4 a = xp[0], b = xp[1];
        u16x8 o;
        o[0] = f2bf(a.x); o[1] = f2bf(a.y); o[2] = f2bf(a.z); o[3] = f2bf(a.w);
        o[4] = f2bf(b.x); o[5] = f2bf(b.y); o[6] = f2bf(b.z); o[7] = f2bf(b.w);
        *((u16x8*)xh + i) = o;
        int2 o8;
        o8.x = pack4(a.x, a.y, a.z, a.w);
        o8.y = pack4(b.x, b.y, b.z, b.w);
        *((int2*)xf8 + i) = o8;
        return;
    }
    if (blockIdx.x == PREP_CVT_NB) {  // weight prep
        for (int k = tid; k < 4096; k += 256) {
            float a = w1rel[k];
            unsigned short hi = f2bf(a);
            whirel[k] = hi;
            wlorel[k] = f2bf(a - bf2f(hi));
            float b = w1root[k];
            unsigned short hb = f2bf(b);
            whiroot[k] = hb;
            wloroot[k] = f2bf(b - bf2f(hb));
        }
        if (tid < 64) {
            float uu = 0.f, vv = 0.f;
            for (int h = 0; h < 64; ++h) {
                float wl = wlin[h];
                uu += wl * w2rel[h * 64 + tid];
                vv += wl * w2root[h * 64 + tid];
            }
            u[tid] = uu;
            v[tid] = vv;
        }
        if (tid == 0) {
            float c = blin[0];
            for (int h = 0; h < 64; ++h) c += wlin[h] * b2rel[h];
            *C = c;
        }
        return;
    }
    if (blockIdx.x < CNT0) {  // dst-bucket histogram
        __shared__ int lh[NBUCK];
        for (int i = tid; i < NBUCK; i += 256) lh[i] = 0;
        __syncthreads();
        int bid2 = blockIdx.x - HIST0;
        for (int e = bid2 * 256 + tid; e < E; e += HIST_NB * 256)
            atomicAdd(&lh[ei[E + e] >> 9], 1);
        __syncthreads();
        for (int i = tid; i < NBUCK; i += 256) {
            int c = lh[i];
            if (c) atomicAdd(&bcount[i], c);
        }
        return;
    }
    {  // per-graph node counts
        __shared__ int lgc[NGRAPHS];
        for (int i = tid; i < NGRAPHS; i += 256) lgc[i] = 0;
        __syncthreads();
        int bid2 = blockIdx.x - CNT0;
        for (int i = bid2 * 256 + tid; i < N_NODES; i += CNT_NB * 256)
            atomicAdd(&lgc[batch[i]], 1);
        __syncthreads();
        for (int i = tid; i < NGRAPHS; i += 256) {
            int c = lgc[i];
            if (c) atomicAdd(&gc[i], (float)c);
        }
    }
}

// ---- kernel 1: ranked bucket fill (with local prefix scan) -----------------
// 4096-edge tile per block: LDS rank per bucket, one global reservation per
// (block,bucket). Bucket base offsets computed locally from bcount (196-wide
// Hillis-Steele) -> no separate scan launch. cursor[] is zero-init (memset);
// final position = local_boff + atomic rank.
__global__ __launch_bounds__(256) void bucket_fill(
    const int* __restrict__ ei, const float* __restrict__ ew,
    const int* __restrict__ bcount, int* __restrict__ cursor,
    int2* __restrict__ ebuf, int E) {
    __shared__ int lh[NBUCK];
    __shared__ int gbase[NBUCK];
    __shared__ int sc[256];
    __shared__ int lbo[NBUCK];
    int tid = threadIdx.x;
    for (int i = tid; i < NBUCK; i += 256) lh[i] = 0;
    int v = (tid < NBUCK) ? bcount[tid] : 0;
    sc[tid] = v;
    __syncthreads();
    for (int off = 1; off < 256; off <<= 1) {
        int x = (tid >= off) ? sc[tid - off] : 0;
        __syncthreads();
        sc[tid] += x;
        __syncthreads();
    }
    if (tid < NBUCK) lbo[tid] = sc[tid] - v;  // exclusive prefix
    __syncthreads();
    int base = blockIdx.x * FILL_TILE;
    int2 rec[FILL_T];
    int meta[FILL_T];
#pragma unroll
    for (int i = 0; i < FILL_T; ++i) {
        int e = base + i * 256 + tid;
        meta[i] = -1;
        if (e < E) {
            int src = ei[e];
            int dst = ei[E + e];
            int b = dst >> 9;
            int r = atomicAdd(&lh[b], 1);  // rank within (block,bucket)
            rec[i].x = src | ((dst & (BN - 1)) << 17);
            rec[i].y = __float_as_int(ew[e]);
            meta[i] = (b << 13) | r;  // r < 4096 fits 13 bits
        }
    }
    __syncthreads();
    for (int i = tid; i < NBUCK; i += 256) {
        int c = lh[i];
        gbase[i] = c ? (lbo[i] + atomicAdd(&cursor[i], c)) : 0;
    }
    __syncthreads();
#pragma unroll
    for (int i = 0; i < FILL_T; ++i) {
        if (meta[i] >= 0) {
            int b = meta[i] >> 13;
            int r = meta[i] & 8191;
            ebuf[gbase[b] + r] = rec[i];
        }
    }
}

// ---- kernel 2: per-bucket degree scan -> row_ptr; place CSR with graph id --
// One block (512 thr) per bucket. Bucket range computed locally from bcount.
// csr.x = src | batch[node]<<17 (g < 128).
__global__ __launch_bounds__(512) void csr_build(
    const int* __restrict__ bcount, const int2* __restrict__ ebuf,
    const int* __restrict__ batch, int* __restrict__ row_ptr,
    int2* __restrict__ csr, int N) {
    __shared__ int s[BN];
    int b = blockIdx.x;
    int t = threadIdx.x;
    // local 196-wide scan of bcount -> beg/end for this bucket
    int vv = (t < NBUCK) ? bcount[t] : 0;
    if (t < 256) s[t] = vv;
    __syncthreads();
    for (int off = 1; off < 256; off <<= 1) {
        int x = (t >= off && t < 256) ? s[t - off] : 0;
        __syncthreads();
        if (t < 256) s[t] += x;
        __syncthreads();
    }
    int beg = (b == 0) ? 0 : s[b - 1];
    int end = s[b];
    __syncthreads();
    s[t] = 0;
    __syncthreads();
    for (int j = beg + t; j < end; j += 512)
        atomicAdd(&s[(ebuf[j].x >> 17) & (BN - 1)], 1);
    __syncthreads();
    int v = s[t];
    for (int off = 1; off < BN; off <<= 1) {
        int x = (t >= off) ? s[t - off] : 0;
        __syncthreads();
        s[t] += x;
        __syncthreads();
    }
    int excl = s[t] - v;
    int gidx = b * BN + t;
    if (gidx <= N) row_ptr[gidx] = beg + excl;  // covers row_ptr[N]=E too
    __syncthreads();
    s[t] = excl;  // becomes intra-bucket cursor
    __syncthreads();
    for (int j = beg + t; j < end; j += 512) {
        int2 rec = ebuf[j];
        int dlo = (rec.x >> 17) & (BN - 1);
        int g = batch[b * BN + dlo];  // L1-hot (1-2 lines per bucket)
        int r = atomicAdd(&s[dlo], 1);
        int2 o;
        o.x = (rec.x & 0x1FFFF) | (g << 17);  // src | graph<<17
        o.y = rec.y;                          // weight bits
        csr[beg + r] = o;
    }
}

// ---- kernel 3: fused gather + MFMA dense -----------------------------------
// One wave per 16-node tile. Phase 1: 16 lane-groups of 4 lanes, one node per
// group, one int4 (16 fp8 features) per lane; fp8 row = 64B = 1 line/edge.
// Unroll-4 with clamped indices: 4 independent row loads in flight per group,
// no divergent tail (invalid slots reload last edge with weight 0, L1-hot).
// Rows land in the per-wave LDS tile as bf16 (stride 72 shorts). Phase 2:
// inline MFMA with hi/lo-split weights (A-root from bf16 xh); epilogue writes
// p and atomicAdds the S-term (q) straight into gq[graph].
__global__ __launch_bounds__(256) void gather_dense_kernel(
    const unsigned char* __restrict__ xf8, const unsigned short* __restrict__ xh,
    const int* __restrict__ row_ptr, const int2* __restrict__ csr,
    const int* __restrict__ batch,
    const unsigned short* __restrict__ whirel,
    const unsigned short* __restrict__ wlorel,
    const unsigned short* __restrict__ whiroot,
    const unsigned short* __restrict__ wloroot,
    const float* __restrict__ b1rel, const float* __restrict__ u,
    const float* __restrict__ v, float* __restrict__ p,
    float* __restrict__ gq, int ntiles) {
    __shared__ unsigned short arow[4][16 * AST];  // 4 waves x 2304B = 9216B
    int lane = threadIdx.x & 63;
    int wv = threadIdx.x >> 6;
    int wave = (blockIdx.x << 2) + wv;
    if (wave >= ntiles) return;  // whole-wave exit; no block barriers used
    unsigned short* my = &arow[wv][0];
    int nb = wave * 16;

    // ---- phase 1: gather 16 node rows into LDS (fp8, 1 line/edge) ----
    {
        int g4 = lane >> 2;  // node 0..15
        int c4 = lane & 3;   // 16-feature chunk
        int node = nb + g4;
        int beg = row_ptr[node], end = row_ptr[node + 1];
        float a[16];
#pragma unroll
        for (int t = 0; t < 16; ++t) a[t] = 0.f;
        const unsigned char* xb = xf8 + (size_t)c4 * 16;
        for (int j = beg; j < end; j += 4) {
            int i1 = min(j + 1, end - 1);
            int i2 = min(j + 2, end - 1);
            int i3 = min(j + 3, end - 1);
            int2 e0 = csr[j];
            int2 e1 = csr[i1];
            int2 e2 = csr[i2];
            int2 e3 = csr[i3];
            int4 r0 = *(const int4*)(xb + (size_t)(e0.x & 0x1FFFF) * 64);
            int4 r1 = *(const int4*)(xb + (size_t)(e1.x & 0x1FFFF) * 64);
            int4 r2 = *(const int4*)(xb + (size_t)(e2.x & 0x1FFFF) * 64);
            int4 r3 = *(const int4*)(xb + (size_t)(e3.x & 0x1FFFF) * 64);
            float w0 = __int_as_float(e0.y);
            float w1 = (j + 1 < end) ? __int_as_float(e1.y) : 0.f;
            float w2 = (j + 2 < end) ? __int_as_float(e2.y) : 0.f;
            float w3 = (j + 3 < end) ? __int_as_float(e3.y) : 0.f;
            fma4(r0.x, w0, a + 0);
            fma4(r0.y, w0, a + 4);
            fma4(r0.z, w0, a + 8);
            fma4(r0.w, w0, a + 12);
            fma4(r1.x, w1, a + 0);
            fma4(r1.y, w1, a + 4);
            fma4(r1.z, w1, a + 8);
            fma4(r1.w, w1, a + 12);
            fma4(r2.x, w2, a + 0);
            fma4(r2.y, w2, a + 4);
            fma4(r2.z, w2, a + 8);
            fma4(r2.w, w2, a + 12);
            fma4(r3.x, w3, a + 0);
            fma4(r3.y, w3, a + 4);
            fma4(r3.z, w3, a + 8);
            fma4(r3.w, w3, a + 12);
        }
        u16x8 o0, o1;
#pragma unroll
        for (int t = 0; t < 8; ++t) {
            o0[t] = f2bf(a[t]);
            o1[t] = f2bf(a[8 + t]);
        }
        *(u16x8*)(my + g4 * AST + c4 * 16) = o0;
        *(u16x8*)(my + g4 * AST + c4 * 16 + 8) = o1;
    }

    // ---- phase 2: MFMA dense on the 16-node tile ----
    int lo4 = lane & 15;
    int quad = lane >> 4;
    f32x4 acc4[4];
#pragma unroll
    for (int t = 0; t < 4; ++t) acc4[t] = (f32x4){0.f, 0.f, 0.f, 0.f};
#pragma unroll
    for (int s = 0; s < 2; ++s) {  // K-step: f in [s*32, s*32+32)
        bf16x8 Aa = *(const bf16x8*)(my + lo4 * AST + s * 32 + quad * 8);
        bf16x8 Ax = *(const bf16x8*)(xh + (size_t)(nb + lo4) * 64 + s * 32 +
                                     quad * 8);
#pragma unroll
        for (int t = 0; t < 4; ++t) {  // h-tile: h in [t*16, t*16+16)
            int off = (t * 16 + lo4) * 64 + s * 32 + quad * 8;
            bf16x8 bhr = *(const bf16x8*)(whirel + off);
            bf16x8 blr = *(const bf16x8*)(wlorel + off);
            bf16x8 bhx = *(const bf16x8*)(whiroot + off);
            bf16x8 blx = *(const bf16x8*)(wloroot + off);
            acc4[t] = __builtin_amdgcn_mfma_f32_16x16x32_bf16(Aa, bhr, acc4[t],
                                                              0, 0, 0);
            acc4[t] = __builtin_amdgcn_mfma_f32_16x16x32_bf16(Aa, blr, acc4[t],
                                                              0, 0, 0);
            acc4[t] = __builtin_amdgcn_mfma_f32_16x16x32_bf16(Ax, bhx, acc4[t],
                                                              0, 0, 0);
            acc4[t] = __builtin_amdgcn_mfma_f32_16x16x32_bf16(Ax, blx, acc4[t],
                                                              0, 0, 0);
        }
    }

    float pc[4] = {0.f, 0.f, 0.f, 0.f};
    float qc[4] = {0.f, 0.f, 0.f, 0.f};
#pragma unroll
    for (int t = 0; t < 4; ++t) {
        float bb = b1rel[t * 16 + lo4];
        float uu = u[t * 16 + lo4];
        float vv = v[t * 16 + lo4];
#pragma unroll
        for (int r = 0; r < 4; ++r) {
            float h1 = fmaxf(acc4[t][r] + bb, 0.f);
            pc[r] += uu * h1;
            qc[r] += vv * h1;
        }
    }
#pragma unroll
    for (int off = 1; off < 16; off <<= 1) {
#pragma unroll
        for (int r = 0; r < 4; ++r) {
            pc[r] += __shfl_xor(pc[r], off);
            qc[r] += __shfl_xor(qc[r], off);
        }
    }
    if (lo4 == 0) {  // lanes 0,16,32,48: nodes nb+quad*4 .. +3
        f32x4 po = {pc[0], pc[1], pc[2], pc[3]};
        *(f32x4*)(p + nb + quad * 4) = po;
#pragma unroll
        for (int r = 0; r < 4; ++r) {
            int g = batch[nb + quad * 4 + r];
            atomicAdd(&gq[g], qc[r]);
        }
    }
}

// ---- kernel 4: T-term pooling + last-block epilogue ------------------------
// Edge-flat over csr (graph id in csr.x bits 17-23, monotone -> curg
// accumulate + LDS flush). Last block to finish (done-counter) computes out[]
// from gp (here), gq (gather), gc (prep).
#define PT_EPT 4
#define PT_EPW (64 * PT_EPT)   // 256 edges per wave
#define PT_NB ((N_EDGES + 4 * PT_EPW - 1) / (4 * PT_EPW))  // 977
__global__ __launch_bounds__(256) void pool_t(
    const int2* __restrict__ csr, const float* __restrict__ p,
    float* __restrict__ gp, const float* __restrict__ gq,
    const float* __restrict__ gc, int* __restrict__ done,
    const float* __restrict__ C, float* __restrict__ out, int E) {
    __shared__ float lbuf[NGRAPHS];
    __shared__ int amLast;
    int tid = threadIdx.x;
    if (tid < NGRAPHS) lbuf[tid] = 0.f;
    __syncthreads();
    int lane = tid & 63;
    int wid = (blockIdx.x * 256 + tid) >> 6;
    int base = wid * PT_EPW;
    float acc = 0.f;
    int curg = -1;
#pragma unroll
    for (int i = 0; i < PT_EPT; ++i) {
        int j = base + i * 64 + lane;
        if (j < E) {
            int2 e = csr[j];
            int g = ((unsigned)e.x) >> 17;
            float val = __int_as_float(e.y) * p[e.x & 0x1FFFF];
            if (g != curg) {
                if (curg >= 0) atomicAdd(&lbuf[curg], acc);
                curg = g;
                acc = 0.f;
            }
            acc += val;
        }
    }
    if (curg >= 0) atomicAdd(&lbuf[curg], acc);
    __syncthreads();
    if (tid < NGRAPHS) {
        float t = lbuf[tid];
        if (t != 0.f) atomicAdd(&gp[tid], t);
    }
    // ---- last-block epilogue ----
    __syncthreads();
    if (tid == 0) {
        __threadfence();  // make this block's atomics visible device-wide
        amLast = (atomicAdd(done, 1) == PT_NB - 1);
    }
    __syncthreads();
    if (amLast) {
        __threadfence();
        if (tid < NGRAPHS) {
            // coherent read-back of device-scope accumulators
            float pv = atomicAdd(&gp[tid], 0.f);
            float qv = atomicAdd((float*)&gq[tid], 0.f);
            float cv = atomicAdd((float*)&gc[tid], 0.f);
            out[tid] = (pv + qv) / fmaxf(cv, 1.f) + C[0];
        }
    }
}

extern "C" void kernel_launch(void* const* d_in, const int* in_sizes, int n_in,
                              void* d_out, int out_size, void* d_ws,
                              size_t ws_size, hipStream_t stream) {
    const float* x      = (const float*)d_in[0];   // [N,64]
    const int*   ei     = (const int*)d_in[1];     // [2,E]
    const float* ew     = (const float*)d_in[2];   // [E]
    const int*   batch  = (const int*)d_in[3];     // [N] sorted
    const float* w1rel  = (const float*)d_in[4];
    const float* b1rel  = (const float*)d_in[5];
    const float* w1root = (const float*)d_in[6];
    const float* w2rel  = (const float*)d_in[7];
    const float* b2rel  = (const float*)d_in[8];
    const float* w2root = (const float*)d_in[9];
    const float* wlin   = (const float*)d_in[10];
    const float* blin   = (const float*)d_in[11];
    float* out = (float*)d_out;

    // ---- workspace layout ----
    // csr [0,8M) | ebuf [8M,16M) | weights/p/misc | row_ptr | xh | xf8.
    char* wsb = (char*)d_ws;
    int2* csr  = (int2*)wsb;                                   // 8 MB
    int2* ebuf = (int2*)(wsb + (size_t)N_EDGES * 8);           // 8 MB
    char* tail = wsb + (size_t)N_EDGES * 16;
    unsigned short* whirel  = (unsigned short*)tail;
    unsigned short* wlorel  = whirel + 4096;
    unsigned short* whiroot = wlorel + 4096;
    unsigned short* wloroot = whiroot + 4096;
    float* p  = (float*)(wloroot + 4096);                      // N
    float* u  = p + N_NODES;                                   // 64
    float* v  = u + 64;                                        // 64
    float* C  = v + 64;                                        // 1
    int*   bcount = (int*)(C + 1);                             // NBUCK
    float* gp = (float*)(bcount + NBUCK);                      // 128
    float* gq = gp + NGRAPHS;                                  // 128
    float* gc = gq + NGRAPHS;                                  // 128
    int*   done   = (int*)(gc + NGRAPHS);                      // 1
    int*   cursor = done + 1;                                  // NBUCK
    int*   row_ptr = cursor + NBUCK;                           // N+1
    unsigned short* xh = (unsigned short*)(row_ptr + N_NODES + 2);  // N*64
    int*   xf8 = (int*)(xh + (size_t)N_NODES * 64);            // N*64 bytes

    // zero: bcount, gp, gq, gc, done, cursor (contiguous)
    hipMemsetAsync(bcount, 0, (2 * NBUCK + 3 * NGRAPHS + 1) * sizeof(int),
                   stream);

    prep_all_kernel<<<PREP_TOTAL, 256, 0, stream>>>(
        x, xh, xf8, w1rel, w1root, w2rel, w2root, wlin, b2rel, blin, whirel,
        wlorel, whiroot, wloroot, u, v, C, ei, bcount, batch, gc, N_EDGES);

    bucket_fill<<<FILL_NB, 256, 0, stream>>>(ei, ew, bcount, cursor, ebuf,
                                             N_EDGES);
    csr_build<<<NBUCK, 512, 0, stream>>>(bcount, ebuf, batch, row_ptr, csr,
                                         N_NODES);

    gather_dense_kernel<<<(NTILES + 3) / 4, 256, 0, stream>>>(
        (const unsigned char*)xf8, xh, row_ptr, csr, batch, whirel, wlorel,
        whiroot, wloroot, b1rel, u, v, p, gq, NTILES);

    pool_t<<<PT_NB, 256, 0, stream>>>(csr, p, gp, gq, gc, done, C, out,
                                      N_EDGES);
}

// Round 4
// 212.141 us; speedup vs baseline: 2.7178x; 2.7178x over previous
//
#include <hip/hip_runtime.h>
#include <hip/hip_bf16.h>

// GNN_65498251264428: 2-layer GraphConv + mean pool + Linear(64,1).
// N=100000 nodes, E=1000000 edges, F=H=64, G=128 graphs.
//
// Layer-2 algebraic collapse (layer 2 is linear):
//   out[g] = (u.T_g + v.S_g)/c_g + (w_lin.b2_rel + b_lin)
//   u = w2_rel^T w_lin, v = w2_root^T w_lin
//   S_g -> per-node scalar q_i = v.h1_i ; T_g -> per-edge w_e * p_{src}
//
// Round 13: R12's per-node atomicAdd(gq[g]) from the gather epilogue was a
// disaster (411us): 100k device-scope fp32 RMWs onto 8 cache lines serialize
// device-wide (WRITE_SIZE 784KB->3.5MB = the RMW line flushes; VALUBusy 2%).
// REVERT (d): gather writes dense p[] and q[] (coalesced f32x4, no atomics);
// S-term back in pool_both via LDS-aggregated atomics (<=128/block, proven
// fine through R11). KEEP: unroll-4 gather (MLP x2), fused cvt8-in-prep,
// launch-free local scans, counts-in-prep, last-block epilogue (in pool).
// memset + 5 kernels.

#define N_NODES 100000
#define N_EDGES 1000000
#define NGRAPHS 128
#define BN 512                              // nodes per bucket
#define NBUCK ((N_NODES + BN - 1) / BN)     // 196
#define FILL_T 16                           // edges per thread in bucket_fill
#define FILL_TILE (256 * FILL_T)            // 4096
#define FILL_NB ((N_EDGES + FILL_TILE - 1) / FILL_TILE)  // 245
#define NTILES (N_NODES / 16)               // 6250 (exact)
#define AST 72                              // LDS row stride in shorts (144B: 16B-aligned frags)

#define PREP_CVT_NB 3125                    // 800000/256 exact
#define HIST0 (PREP_CVT_NB + 1)             // 3126
#define HIST_NB 256
#define CNT0 (HIST0 + HIST_NB)              // 3382
#define CNT_NB 64
#define PREP_TOTAL (CNT0 + CNT_NB)          // 3446

typedef __attribute__((ext_vector_type(8))) short bf16x8;
typedef __attribute__((ext_vector_type(8))) unsigned short u16x8;
typedef __attribute__((ext_vector_type(4))) float f32x4;
typedef __attribute__((ext_vector_type(2))) float f32x2;

__device__ __forceinline__ unsigned short f2bf(float f) {
    unsigned u = __float_as_uint(f);
    unsigned r = (u + 0x7FFFu + ((u >> 16) & 1u)) >> 16;  // RNE
    return (unsigned short)r;
}
__device__ __forceinline__ float bf2f(unsigned short h) {
    return __uint_as_float(((unsigned)h) << 16);
}
// 4 fp8 (one dword) -> f32 via HW cvt, FMA into a[0..3]
__device__ __forceinline__ void fma4(int w, float wt, float* a) {
    f32x2 lo = __builtin_amdgcn_cvt_pk_f32_fp8(w, false);
    f32x2 hi = __builtin_amdgcn_cvt_pk_f32_fp8(w, true);
    a[0] += wt * lo[0];
    a[1] += wt * lo[1];
    a[2] += wt * hi[0];
    a[3] += wt * hi[1];
}
__device__ __forceinline__ int pack4(float f0, float f1, float f2, float f3) {
    int w = __builtin_amdgcn_cvt_pk_fp8_f32(f0, f1, 0, false);
    w = __builtin_amdgcn_cvt_pk_fp8_f32(f2, f3, w, true);
    return w;
}

// ---- kernel 0: fused x->{bf16,fp8} cvt + weight prep + dst hist + batch cnt
__global__ __launch_bounds__(256) void prep_all_kernel(
    const float* __restrict__ x, unsigned short* __restrict__ xh,
    int* __restrict__ xf8,
    const float* __restrict__ w1rel, const float* __restrict__ w1root,
    const float* __restrict__ w2rel, const float* __restrict__ w2root,
    const float* __restrict__ wlin, const float* __restrict__ b2rel,
    const float* __restrict__ blin, unsigned short* __restrict__ whirel,
    unsigned short* __restrict__ wlorel, unsigned short* __restrict__ whiroot,
    unsigned short* __restrict__ wloroot, float* __restrict__ u,
    float* __restrict__ v, float* __restrict__ C,
    const int* __restrict__ ei, int* __restrict__ bcount,
    const int* __restrict__ batch, float* __restrict__ gc, int E) {
    int tid = threadIdx.x;
    if (blockIdx.x < PREP_CVT_NB) {  // cvt part: 8 floats/thread
        int i = blockIdx.x * 256 + tid;
        const float4* xp = (const float4*)x + (size_t)i * 2;
        float4 a = xp[0], b = xp[1];
        u16x8 o;
        o[0] = f2bf(a.x); o[1] = f2bf(a.y); o[2] = f2bf(a.z); o[3] = f2bf(a.w);
        o[4] = f2bf(b.x); o[5] = f2bf(b.y); o[6] = f2bf(b.z); o[7] = f2bf(b.w);
        *((u16x8*)xh + i) = o;
        int2 o8;
        o8.x = pack4(a.x, a.y, a.z, a.w);
        o8.y = pack4(b.x, b.y, b.z, b.w);
        *((int2*)xf8 + i) = o8;
        return;
    }
    if (blockIdx.x == PREP_CVT_NB) {  // weight prep
        for (int k = tid; k < 4096; k += 256) {
            float a = w1rel[k];
            unsigned short hi = f2bf(a);
            whirel[k] = hi;
            wlorel[k] = f2bf(a - bf2f(hi));
            float b = w1root[k];
            unsigned short hb = f2bf(b);
            whiroot[k] = hb;
            wloroot[k] = f2bf(b - bf2f(hb));
        }
        if (tid < 64) {
            float uu = 0.f, vv = 0.f;
            for (int h = 0; h < 64; ++h) {
                float wl = wlin[h];
                uu += wl * w2rel[h * 64 + tid];
                vv += wl * w2root[h * 64 + tid];
            }
            u[tid] = uu;
            v[tid] = vv;
        }
        if (tid == 0) {
            float c = blin[0];
            for (int h = 0; h < 64; ++h) c += wlin[h] * b2rel[h];
            *C = c;
        }
        return;
    }
    if (blockIdx.x < CNT0) {  // dst-bucket histogram
        __shared__ int lh[NBUCK];
        for (int i = tid; i < NBUCK; i += 256) lh[i] = 0;
        __syncthreads();
        int bid2 = blockIdx.x - HIST0;
        for (int e = bid2 * 256 + tid; e < E; e += HIST_NB * 256)
            atomicAdd(&lh[ei[E + e] >> 9], 1);
        __syncthreads();
        for (int i = tid; i < NBUCK; i += 256) {
            int c = lh[i];
            if (c) atomicAdd(&bcount[i], c);
        }
        return;
    }
    {  // per-graph node counts
        __shared__ int lgc[NGRAPHS];
        for (int i = tid; i < NGRAPHS; i += 256) lgc[i] = 0;
        __syncthreads();
        int bid2 = blockIdx.x - CNT0;
        for (int i = bid2 * 256 + tid; i < N_NODES; i += CNT_NB * 256)
            atomicAdd(&lgc[batch[i]], 1);
        __syncthreads();
        for (int i = tid; i < NGRAPHS; i += 256) {
            int c = lgc[i];
            if (c) atomicAdd(&gc[i], (float)c);
        }
    }
}

// ---- kernel 1: ranked bucket fill (with local prefix scan) -----------------
// 4096-edge tile per block: LDS rank per bucket, one global reservation per
// (block,bucket). Bucket base offsets computed locally from bcount (196-wide
// Hillis-Steele) -> no separate scan launch. cursor[] is zero-init (memset);
// final position = local_boff + atomic rank.
__global__ __launch_bounds__(256) void bucket_fill(
    const int* __restrict__ ei, const float* __restrict__ ew,
    const int* __restrict__ bcount, int* __restrict__ cursor,
    int2* __restrict__ ebuf, int E) {
    __shared__ int lh[NBUCK];
    __shared__ int gbase[NBUCK];
    __shared__ int sc[256];
    __shared__ int lbo[NBUCK];
    int tid = threadIdx.x;
    for (int i = tid; i < NBUCK; i += 256) lh[i] = 0;
    int v = (tid < NBUCK) ? bcount[tid] : 0;
    sc[tid] = v;
    __syncthreads();
    for (int off = 1; off < 256; off <<= 1) {
        int x = (tid >= off) ? sc[tid - off] : 0;
        __syncthreads();
        sc[tid] += x;
        __syncthreads();
    }
    if (tid < NBUCK) lbo[tid] = sc[tid] - v;  // exclusive prefix
    __syncthreads();
    int base = blockIdx.x * FILL_TILE;
    int2 rec[FILL_T];
    int meta[FILL_T];
#pragma unroll
    for (int i = 0; i < FILL_T; ++i) {
        int e = base + i * 256 + tid;
        meta[i] = -1;
        if (e < E) {
            int src = ei[e];
            int dst = ei[E + e];
            int b = dst >> 9;
            int r = atomicAdd(&lh[b], 1);  // rank within (block,bucket)
            rec[i].x = src | ((dst & (BN - 1)) << 17);
            rec[i].y = __float_as_int(ew[e]);
            meta[i] = (b << 13) | r;  // r < 4096 fits 13 bits
        }
    }
    __syncthreads();
    for (int i = tid; i < NBUCK; i += 256) {
        int c = lh[i];
        gbase[i] = c ? (lbo[i] + atomicAdd(&cursor[i], c)) : 0;
    }
    __syncthreads();
#pragma unroll
    for (int i = 0; i < FILL_T; ++i) {
        if (meta[i] >= 0) {
            int b = meta[i] >> 13;
            int r = meta[i] & 8191;
            ebuf[gbase[b] + r] = rec[i];
        }
    }
}

// ---- kernel 2: per-bucket degree scan -> row_ptr; place CSR with graph id --
// One block (512 thr) per bucket. Bucket range computed locally from bcount.
// csr.x = src | batch[node]<<17 (g < 128).
__global__ __launch_bounds__(512) void csr_build(
    const int* __restrict__ bcount, const int2* __restrict__ ebuf,
    const int* __restrict__ batch, int* __restrict__ row_ptr,
    int2* __restrict__ csr, int N) {
    __shared__ int s[BN];
    int b = blockIdx.x;
    int t = threadIdx.x;
    // local 196-wide scan of bcount -> beg/end for this bucket
    int vv = (t < NBUCK) ? bcount[t] : 0;
    if (t < 256) s[t] = vv;
    __syncthreads();
    for (int off = 1; off < 256; off <<= 1) {
        int x = (t >= off && t < 256) ? s[t - off] : 0;
        __syncthreads();
        if (t < 256) s[t] += x;
        __syncthreads();
    }
    int beg = (b == 0) ? 0 : s[b - 1];
    int end = s[b];
    __syncthreads();
    s[t] = 0;
    __syncthreads();
    for (int j = beg + t; j < end; j += 512)
        atomicAdd(&s[(ebuf[j].x >> 17) & (BN - 1)], 1);
    __syncthreads();
    int v = s[t];
    for (int off = 1; off < BN; off <<= 1) {
        int x = (t >= off) ? s[t - off] : 0;
        __syncthreads();
        s[t] += x;
        __syncthreads();
    }
    int excl = s[t] - v;
    int gidx = b * BN + t;
    if (gidx <= N) row_ptr[gidx] = beg + excl;  // covers row_ptr[N]=E too
    __syncthreads();
    s[t] = excl;  // becomes intra-bucket cursor
    __syncthreads();
    for (int j = beg + t; j < end; j += 512) {
        int2 rec = ebuf[j];
        int dlo = (rec.x >> 17) & (BN - 1);
        int g = batch[b * BN + dlo];  // L1-hot (1-2 lines per bucket)
        int r = atomicAdd(&s[dlo], 1);
        int2 o;
        o.x = (rec.x & 0x1FFFF) | (g << 17);  // src | graph<<17
        o.y = rec.y;                          // weight bits
        csr[beg + r] = o;
    }
}

// ---- kernel 3: fused gather + MFMA dense -----------------------------------
// One wave per 16-node tile. Phase 1: 16 lane-groups of 4 lanes, one node per
// group, one int4 (16 fp8 features) per lane; fp8 row = 64B = 1 line/edge.
// Unroll-4 with clamped indices: 4 independent row loads in flight per group,
// no divergent tail (invalid slots reload last edge with weight 0, L1-hot).
// Rows land in the per-wave LDS tile as bf16 (stride 72 shorts). Phase 2:
// inline MFMA with hi/lo-split weights (A-root from bf16 xh); epilogue writes
// dense p[] and q[] (coalesced f32x4 stores -- NO atomics; R12's per-node
// gq atomics serialized the whole device).
__global__ __launch_bounds__(256) void gather_dense_kernel(
    const unsigned char* __restrict__ xf8, const unsigned short* __restrict__ xh,
    const int* __restrict__ row_ptr, const int2* __restrict__ csr,
    const unsigned short* __restrict__ whirel,
    const unsigned short* __restrict__ wlorel,
    const unsigned short* __restrict__ whiroot,
    const unsigned short* __restrict__ wloroot,
    const float* __restrict__ b1rel, const float* __restrict__ u,
    const float* __restrict__ v, float* __restrict__ p, float* __restrict__ q,
    int ntiles) {
    __shared__ unsigned short arow[4][16 * AST];  // 4 waves x 2304B = 9216B
    int lane = threadIdx.x & 63;
    int wv = threadIdx.x >> 6;
    int wave = (blockIdx.x << 2) + wv;
    if (wave >= ntiles) return;  // whole-wave exit; no block barriers used
    unsigned short* my = &arow[wv][0];
    int nb = wave * 16;

    // ---- phase 1: gather 16 node rows into LDS (fp8, 1 line/edge) ----
    {
        int g4 = lane >> 2;  // node 0..15
        int c4 = lane & 3;   // 16-feature chunk
        int node = nb + g4;
        int beg = row_ptr[node], end = row_ptr[node + 1];
        float a[16];
#pragma unroll
        for (int t = 0; t < 16; ++t) a[t] = 0.f;
        const unsigned char* xb = xf8 + (size_t)c4 * 16;
        for (int j = beg; j < end; j += 4) {
            int i1 = min(j + 1, end - 1);
            int i2 = min(j + 2, end - 1);
            int i3 = min(j + 3, end - 1);
            int2 e0 = csr[j];
            int2 e1 = csr[i1];
            int2 e2 = csr[i2];
            int2 e3 = csr[i3];
            int4 r0 = *(const int4*)(xb + (size_t)(e0.x & 0x1FFFF) * 64);
            int4 r1 = *(const int4*)(xb + (size_t)(e1.x & 0x1FFFF) * 64);
            int4 r2 = *(const int4*)(xb + (size_t)(e2.x & 0x1FFFF) * 64);
            int4 r3 = *(const int4*)(xb + (size_t)(e3.x & 0x1FFFF) * 64);
            float w0 = __int_as_float(e0.y);
            float w1 = (j + 1 < end) ? __int_as_float(e1.y) : 0.f;
            float w2 = (j + 2 < end) ? __int_as_float(e2.y) : 0.f;
            float w3 = (j + 3 < end) ? __int_as_float(e3.y) : 0.f;
            fma4(r0.x, w0, a + 0);
            fma4(r0.y, w0, a + 4);
            fma4(r0.z, w0, a + 8);
            fma4(r0.w, w0, a + 12);
            fma4(r1.x, w1, a + 0);
            fma4(r1.y, w1, a + 4);
            fma4(r1.z, w1, a + 8);
            fma4(r1.w, w1, a + 12);
            fma4(r2.x, w2, a + 0);
            fma4(r2.y, w2, a + 4);
            fma4(r2.z, w2, a + 8);
            fma4(r2.w, w2, a + 12);
            fma4(r3.x, w3, a + 0);
            fma4(r3.y, w3, a + 4);
            fma4(r3.z, w3, a + 8);
            fma4(r3.w, w3, a + 12);
        }
        u16x8 o0, o1;
#pragma unroll
        for (int t = 0; t < 8; ++t) {
            o0[t] = f2bf(a[t]);
            o1[t] = f2bf(a[8 + t]);
        }
        *(u16x8*)(my + g4 * AST + c4 * 16) = o0;
        *(u16x8*)(my + g4 * AST + c4 * 16 + 8) = o1;
    }

    // ---- phase 2: MFMA dense on the 16-node tile ----
    int lo4 = lane & 15;
    int quad = lane >> 4;
    f32x4 acc4[4];
#pragma unroll
    for (int t = 0; t < 4; ++t) acc4[t] = (f32x4){0.f, 0.f, 0.f, 0.f};
#pragma unroll
    for (int s = 0; s < 2; ++s) {  // K-step: f in [s*32, s*32+32)
        bf16x8 Aa = *(const bf16x8*)(my + lo4 * AST + s * 32 + quad * 8);
        bf16x8 Ax = *(const bf16x8*)(xh + (size_t)(nb + lo4) * 64 + s * 32 +
                                     quad * 8);
#pragma unroll
        for (int t = 0; t < 4; ++t) {  // h-tile: h in [t*16, t*16+16)
            int off = (t * 16 + lo4) * 64 + s * 32 + quad * 8;
            bf16x8 bhr = *(const bf16x8*)(whirel + off);
            bf16x8 blr = *(const bf16x8*)(wlorel + off);
            bf16x8 bhx = *(const bf16x8*)(whiroot + off);
            bf16x8 blx = *(const bf16x8*)(wloroot + off);
            acc4[t] = __builtin_amdgcn_mfma_f32_16x16x32_bf16(Aa, bhr, acc4[t],
                                                              0, 0, 0);
            acc4[t] = __builtin_amdgcn_mfma_f32_16x16x32_bf16(Aa, blr, acc4[t],
                                                              0, 0, 0);
            acc4[t] = __builtin_amdgcn_mfma_f32_16x16x32_bf16(Ax, bhx, acc4[t],
                                                              0, 0, 0);
            acc4[t] = __builtin_amdgcn_mfma_f32_16x16x32_bf16(Ax, blx, acc4[t],
                                                              0, 0, 0);
        }
    }

    float pc[4] = {0.f, 0.f, 0.f, 0.f};
    float qc[4] = {0.f, 0.f, 0.f, 0.f};
#pragma unroll
    for (int t = 0; t < 4; ++t) {
        float bb = b1rel[t * 16 + lo4];
        float uu = u[t * 16 + lo4];
        float vv = v[t * 16 + lo4];
#pragma unroll
        for (int r = 0; r < 4; ++r) {
            float h1 = fmaxf(acc4[t][r] + bb, 0.f);
            pc[r] += uu * h1;
            qc[r] += vv * h1;
        }
    }
#pragma unroll
    for (int off = 1; off < 16; off <<= 1) {
#pragma unroll
        for (int r = 0; r < 4; ++r) {
            pc[r] += __shfl_xor(pc[r], off);
            qc[r] += __shfl_xor(qc[r], off);
        }
    }
    if (lo4 == 0) {  // lanes 0,16,32,48: nodes nb+quad*4 .. +3
        f32x4 po = {pc[0], pc[1], pc[2], pc[3]};
        f32x4 qo = {qc[0], qc[1], qc[2], qc[3]};
        *(f32x4*)(p + nb + quad * 4) = po;
        *(f32x4*)(q + nb + quad * 4) = qo;
    }
}

// ---- kernel 4: fused pooling + last-block epilogue -------------------------
// blocks [0, PT_NB): T_g edge-flat over csr (graph id in csr.x bits 17-23,
// monotone -> curg accumulate + LDS flush). blocks [PT_NB, PT_NB+PS_NB):
// S_g node-flat (counts already in gc from prep). Last block to finish
// (done-counter) computes out[].
#define PT_EPT 4
#define PT_EPW (64 * PT_EPT)   // 256 edges per wave
#define PT_NB ((N_EDGES + 4 * PT_EPW - 1) / (4 * PT_EPW))  // 977
#define PS_NB 98
__global__ __launch_bounds__(256) void pool_both(
    const int2* __restrict__ csr, const float* __restrict__ p,
    const float* __restrict__ q, const int* __restrict__ batch,
    float* __restrict__ gp, float* __restrict__ gq,
    const float* __restrict__ gc, int* __restrict__ done,
    const float* __restrict__ C, float* __restrict__ out, int E, int N) {
    __shared__ float lbuf[NGRAPHS];
    __shared__ int amLast;
    int tid = threadIdx.x;
    if (tid < NGRAPHS) lbuf[tid] = 0.f;
    __syncthreads();
    if (blockIdx.x < PT_NB) {
        int lane = tid & 63;
        int wid = (blockIdx.x * 256 + tid) >> 6;
        int base = wid * PT_EPW;
        float acc = 0.f;
        int curg = -1;
#pragma unroll
        for (int i = 0; i < PT_EPT; ++i) {
            int j = base + i * 64 + lane;
            if (j < E) {
                int2 e = csr[j];
                int g = ((unsigned)e.x) >> 17;
                float val = __int_as_float(e.y) * p[e.x & 0x1FFFF];
                if (g != curg) {
                    if (curg >= 0) atomicAdd(&lbuf[curg], acc);
                    curg = g;
                    acc = 0.f;
                }
                acc += val;
            }
        }
        if (curg >= 0) atomicAdd(&lbuf[curg], acc);
        __syncthreads();
        if (tid < NGRAPHS) {
            float t = lbuf[tid];
            if (t != 0.f) atomicAdd(&gp[tid], t);
        }
    } else {
        int bid = blockIdx.x - PT_NB;
        for (int i = bid * 256 + tid; i < N; i += PS_NB * 256) {
            atomicAdd(&lbuf[batch[i]], q[i]);
        }
        __syncthreads();
        if (tid < NGRAPHS) {
            float t = lbuf[tid];
            if (t != 0.f) atomicAdd(&gq[tid], t);
        }
    }
    // ---- last-block epilogue ----
    __syncthreads();
    if (tid == 0) {
        __threadfence();  // make this block's atomics visible device-wide
        amLast = (atomicAdd(done, 1) == PT_NB + PS_NB - 1);
    }
    __syncthreads();
    if (amLast) {
        __threadfence();
        if (tid < NGRAPHS) {
            // coherent read-back of device-scope accumulators
            float pv = atomicAdd(&gp[tid], 0.f);
            float qv = atomicAdd(&gq[tid], 0.f);
            float cv = atomicAdd((float*)&gc[tid], 0.f);
            out[tid] = (pv + qv) / fmaxf(cv, 1.f) + C[0];
        }
    }
}

extern "C" void kernel_launch(void* const* d_in, const int* in_sizes, int n_in,
                              void* d_out, int out_size, void* d_ws,
                              size_t ws_size, hipStream_t stream) {
    const float* x      = (const float*)d_in[0];   // [N,64]
    const int*   ei     = (const int*)d_in[1];     // [2,E]
    const float* ew     = (const float*)d_in[2];   // [E]
    const int*   batch  = (const int*)d_in[3];     // [N] sorted
    const float* w1rel  = (const float*)d_in[4];
    const float* b1rel  = (const float*)d_in[5];
    const float* w1root = (const float*)d_in[6];
    const float* w2rel  = (const float*)d_in[7];
    const float* b2rel  = (const float*)d_in[8];
    const float* w2root = (const float*)d_in[9];
    const float* wlin   = (const float*)d_in[10];
    const float* blin   = (const float*)d_in[11];
    float* out = (float*)d_out;

    // ---- workspace layout ----
    // csr [0,8M) | ebuf [8M,16M) | weights/p/q/misc | row_ptr | xh | xf8.
    char* wsb = (char*)d_ws;
    int2* csr  = (int2*)wsb;                                   // 8 MB
    int2* ebuf = (int2*)(wsb + (size_t)N_EDGES * 8);           // 8 MB
    char* tail = wsb + (size_t)N_EDGES * 16;
    unsigned short* whirel  = (unsigned short*)tail;
    unsigned short* wlorel  = whirel + 4096;
    unsigned short* whiroot = wlorel + 4096;
    unsigned short* wloroot = whiroot + 4096;
    float* p  = (float*)(wloroot + 4096);                      // N
    float* q  = p + N_NODES;                                   // N
    float* u  = q + N_NODES;                                   // 64
    float* v  = u + 64;                                        // 64
    float* C  = v + 64;                                        // 1
    int*   bcount = (int*)(C + 1);                             // NBUCK
    float* gp = (float*)(bcount + NBUCK);                      // 128
    float* gq = gp + NGRAPHS;                                  // 128
    float* gc = gq + NGRAPHS;                                  // 128
    int*   done   = (int*)(gc + NGRAPHS);                      // 1
    int*   cursor = done + 1;                                  // NBUCK
    int*   row_ptr = cursor + NBUCK;                           // N+1
    unsigned short* xh = (unsigned short*)(row_ptr + N_NODES + 2);  // N*64
    int*   xf8 = (int*)(xh + (size_t)N_NODES * 64);            // N*64 bytes

    // zero: bcount, gp, gq, gc, done, cursor (contiguous)
    hipMemsetAsync(bcount, 0, (2 * NBUCK + 3 * NGRAPHS + 1) * sizeof(int),
                   stream);

    prep_all_kernel<<<PREP_TOTAL, 256, 0, stream>>>(
        x, xh, xf8, w1rel, w1root, w2rel, w2root, wlin, b2rel, blin, whirel,
        wlorel, whiroot, wloroot, u, v, C, ei, bcount, batch, gc, N_EDGES);

    bucket_fill<<<FILL_NB, 256, 0, stream>>>(ei, ew, bcount, cursor, ebuf,
                                             N_EDGES);
    csr_build<<<NBUCK, 512, 0, stream>>>(bcount, ebuf, batch, row_ptr, csr,
                                         N_NODES);

    gather_dense_kernel<<<(NTILES + 3) / 4, 256, 0, stream>>>(
        (const unsigned char*)xf8, xh, row_ptr, csr, whirel, wlorel, whiroot,
        wloroot, b1rel, u, v, p, q, NTILES);

    pool_both<<<PT_NB + PS_NB, 256, 0, stream>>>(csr, p, q, batch, gp, gq, gc,
                                                 done, C, out, N_EDGES,
                                                 N_NODES);
}

// Round 5
// 209.011 us; speedup vs baseline: 2.7585x; 1.0150x over previous
//
#include <hip/hip_runtime.h>
#include <hip/hip_bf16.h>

// GNN_65498251264428: 2-layer GraphConv + mean pool + Linear(64,1).
// N=100000 nodes, E=1000000 edges, F=H=64, G=128 graphs.
//
// Layer-2 algebraic collapse (layer 2 is linear):
//   out[g] = (u.T_g + v.S_g)/c_g + (w_lin.b2_rel + b_lin)
//   u = w2_rel^T w_lin, v = w2_root^T w_lin
//   S_g -> per-node scalar q_i = v.h1_i ; T_g -> per-edge w_e * p_{src}
//
// Round 14: R13 re-established 46us gather. Model: gather is bound by
// outstanding-miss capacity x miss latency (unroll 2->4 null, VALU halving
// null, but fetched-line count tracks cost). R13's clamped tails re-fetched
// e[end-1]'s row (+15MB FETCH). Fix: clamp invalid slots to j (line already
// in flight this iteration -> MSHR-merge, no extra fetch, w=0 kills the
// contribution, data finite). This is also the cheap falsifiable test of the
// miss-count model: fetch -24% should give dur -10..-20% if right.
// Also: pool PT_EPT 4->8 (halves T-block count and LDS flush overhead).
// memset + 5 kernels.

#define N_NODES 100000
#define N_EDGES 1000000
#define NGRAPHS 128
#define BN 512                              // nodes per bucket
#define NBUCK ((N_NODES + BN - 1) / BN)     // 196
#define FILL_T 16                           // edges per thread in bucket_fill
#define FILL_TILE (256 * FILL_T)            // 4096
#define FILL_NB ((N_EDGES + FILL_TILE - 1) / FILL_TILE)  // 245
#define NTILES (N_NODES / 16)               // 6250 (exact)
#define AST 72                              // LDS row stride in shorts (144B: 16B-aligned frags)

#define PREP_CVT_NB 3125                    // 800000/256 exact
#define HIST0 (PREP_CVT_NB + 1)             // 3126
#define HIST_NB 256
#define CNT0 (HIST0 + HIST_NB)              // 3382
#define CNT_NB 64
#define PREP_TOTAL (CNT0 + CNT_NB)          // 3446

typedef __attribute__((ext_vector_type(8))) short bf16x8;
typedef __attribute__((ext_vector_type(8))) unsigned short u16x8;
typedef __attribute__((ext_vector_type(4))) float f32x4;
typedef __attribute__((ext_vector_type(2))) float f32x2;

__device__ __forceinline__ unsigned short f2bf(float f) {
    unsigned u = __float_as_uint(f);
    unsigned r = (u + 0x7FFFu + ((u >> 16) & 1u)) >> 16;  // RNE
    return (unsigned short)r;
}
__device__ __forceinline__ float bf2f(unsigned short h) {
    return __uint_as_float(((unsigned)h) << 16);
}
// 4 fp8 (one dword) -> f32 via HW cvt, FMA into a[0..3]
__device__ __forceinline__ void fma4(int w, float wt, float* a) {
    f32x2 lo = __builtin_amdgcn_cvt_pk_f32_fp8(w, false);
    f32x2 hi = __builtin_amdgcn_cvt_pk_f32_fp8(w, true);
    a[0] += wt * lo[0];
    a[1] += wt * lo[1];
    a[2] += wt * hi[0];
    a[3] += wt * hi[1];
}
__device__ __forceinline__ int pack4(float f0, float f1, float f2, float f3) {
    int w = __builtin_amdgcn_cvt_pk_fp8_f32(f0, f1, 0, false);
    w = __builtin_amdgcn_cvt_pk_fp8_f32(f2, f3, w, true);
    return w;
}

// ---- kernel 0: fused x->{bf16,fp8} cvt + weight prep + dst hist + batch cnt
__global__ __launch_bounds__(256) void prep_all_kernel(
    const float* __restrict__ x, unsigned short* __restrict__ xh,
    int* __restrict__ xf8,
    const float* __restrict__ w1rel, const float* __restrict__ w1root,
    const float* __restrict__ w2rel, const float* __restrict__ w2root,
    const float* __restrict__ wlin, const float* __restrict__ b2rel,
    const float* __restrict__ blin, unsigned short* __restrict__ whirel,
    unsigned short* __restrict__ wlorel, unsigned short* __restrict__ whiroot,
    unsigned short* __restrict__ wloroot, float* __restrict__ u,
    float* __restrict__ v, float* __restrict__ C,
    const int* __restrict__ ei, int* __restrict__ bcount,
    const int* __restrict__ batch, float* __restrict__ gc, int E) {
    int tid = threadIdx.x;
    if (blockIdx.x < PREP_CVT_NB) {  // cvt part: 8 floats/thread
        int i = blockIdx.x * 256 + tid;
        const float4* xp = (const float4*)x + (size_t)i * 2;
        float4 a = xp[0], b = xp[1];
        u16x8 o;
        o[0] = f2bf(a.x); o[1] = f2bf(a.y); o[2] = f2bf(a.z); o[3] = f2bf(a.w);
        o[4] = f2bf(b.x); o[5] = f2bf(b.y); o[6] = f2bf(b.z); o[7] = f2bf(b.w);
        *((u16x8*)xh + i) = o;
        int2 o8;
        o8.x = pack4(a.x, a.y, a.z, a.w);
        o8.y = pack4(b.x, b.y, b.z, b.w);
        *((int2*)xf8 + i) = o8;
        return;
    }
    if (blockIdx.x == PREP_CVT_NB) {  // weight prep
        for (int k = tid; k < 4096; k += 256) {
            float a = w1rel[k];
            unsigned short hi = f2bf(a);
            whirel[k] = hi;
            wlorel[k] = f2bf(a - bf2f(hi));
            float b = w1root[k];
            unsigned short hb = f2bf(b);
            whiroot[k] = hb;
            wloroot[k] = f2bf(b - bf2f(hb));
        }
        if (tid < 64) {
            float uu = 0.f, vv = 0.f;
            for (int h = 0; h < 64; ++h) {
                float wl = wlin[h];
                uu += wl * w2rel[h * 64 + tid];
                vv += wl * w2root[h * 64 + tid];
            }
            u[tid] = uu;
            v[tid] = vv;
        }
        if (tid == 0) {
            float c = blin[0];
            for (int h = 0; h < 64; ++h) c += wlin[h] * b2rel[h];
            *C = c;
        }
        return;
    }
    if (blockIdx.x < CNT0) {  // dst-bucket histogram
        __shared__ int lh[NBUCK];
        for (int i = tid; i < NBUCK; i += 256) lh[i] = 0;
        __syncthreads();
        int bid2 = blockIdx.x - HIST0;
        for (int e = bid2 * 256 + tid; e < E; e += HIST_NB * 256)
            atomicAdd(&lh[ei[E + e] >> 9], 1);
        __syncthreads();
        for (int i = tid; i < NBUCK; i += 256) {
            int c = lh[i];
            if (c) atomicAdd(&bcount[i], c);
        }
        return;
    }
    {  // per-graph node counts
        __shared__ int lgc[NGRAPHS];
        for (int i = tid; i < NGRAPHS; i += 256) lgc[i] = 0;
        __syncthreads();
        int bid2 = blockIdx.x - CNT0;
        for (int i = bid2 * 256 + tid; i < N_NODES; i += CNT_NB * 256)
            atomicAdd(&lgc[batch[i]], 1);
        __syncthreads();
        for (int i = tid; i < NGRAPHS; i += 256) {
            int c = lgc[i];
            if (c) atomicAdd(&gc[i], (float)c);
        }
    }
}

// ---- kernel 1: ranked bucket fill (with local prefix scan) -----------------
// 4096-edge tile per block: LDS rank per bucket, one global reservation per
// (block,bucket). Bucket base offsets computed locally from bcount (196-wide
// Hillis-Steele) -> no separate scan launch. cursor[] is zero-init (memset);
// final position = local_boff + atomic rank.
__global__ __launch_bounds__(256) void bucket_fill(
    const int* __restrict__ ei, const float* __restrict__ ew,
    const int* __restrict__ bcount, int* __restrict__ cursor,
    int2* __restrict__ ebuf, int E) {
    __shared__ int lh[NBUCK];
    __shared__ int gbase[NBUCK];
    __shared__ int sc[256];
    __shared__ int lbo[NBUCK];
    int tid = threadIdx.x;
    for (int i = tid; i < NBUCK; i += 256) lh[i] = 0;
    int v = (tid < NBUCK) ? bcount[tid] : 0;
    sc[tid] = v;
    __syncthreads();
    for (int off = 1; off < 256; off <<= 1) {
        int x = (tid >= off) ? sc[tid - off] : 0;
        __syncthreads();
        sc[tid] += x;
        __syncthreads();
    }
    if (tid < NBUCK) lbo[tid] = sc[tid] - v;  // exclusive prefix
    __syncthreads();
    int base = blockIdx.x * FILL_TILE;
    int2 rec[FILL_T];
    int meta[FILL_T];
#pragma unroll
    for (int i = 0; i < FILL_T; ++i) {
        int e = base + i * 256 + tid;
        meta[i] = -1;
        if (e < E) {
            int src = ei[e];
            int dst = ei[E + e];
            int b = dst >> 9;
            int r = atomicAdd(&lh[b], 1);  // rank within (block,bucket)
            rec[i].x = src | ((dst & (BN - 1)) << 17);
            rec[i].y = __float_as_int(ew[e]);
            meta[i] = (b << 13) | r;  // r < 4096 fits 13 bits
        }
    }
    __syncthreads();
    for (int i = tid; i < NBUCK; i += 256) {
        int c = lh[i];
        gbase[i] = c ? (lbo[i] + atomicAdd(&cursor[i], c)) : 0;
    }
    __syncthreads();
#pragma unroll
    for (int i = 0; i < FILL_T; ++i) {
        if (meta[i] >= 0) {
            int b = meta[i] >> 13;
            int r = meta[i] & 8191;
            ebuf[gbase[b] + r] = rec[i];
        }
    }
}

// ---- kernel 2: per-bucket degree scan -> row_ptr; place CSR with graph id --
// One block (512 thr) per bucket. Bucket range computed locally from bcount.
// csr.x = src | batch[node]<<17 (g < 128).
__global__ __launch_bounds__(512) void csr_build(
    const int* __restrict__ bcount, const int2* __restrict__ ebuf,
    const int* __restrict__ batch, int* __restrict__ row_ptr,
    int2* __restrict__ csr, int N) {
    __shared__ int s[BN];
    int b = blockIdx.x;
    int t = threadIdx.x;
    // local 196-wide scan of bcount -> beg/end for this bucket
    int vv = (t < NBUCK) ? bcount[t] : 0;
    if (t < 256) s[t] = vv;
    __syncthreads();
    for (int off = 1; off < 256; off <<= 1) {
        int x = (t >= off && t < 256) ? s[t - off] : 0;
        __syncthreads();
        if (t < 256) s[t] += x;
        __syncthreads();
    }
    int beg = (b == 0) ? 0 : s[b - 1];
    int end = s[b];
    __syncthreads();
    s[t] = 0;
    __syncthreads();
    for (int j = beg + t; j < end; j += 512)
        atomicAdd(&s[(ebuf[j].x >> 17) & (BN - 1)], 1);
    __syncthreads();
    int v = s[t];
    for (int off = 1; off < BN; off <<= 1) {
        int x = (t >= off) ? s[t - off] : 0;
        __syncthreads();
        s[t] += x;
        __syncthreads();
    }
    int excl = s[t] - v;
    int gidx = b * BN + t;
    if (gidx <= N) row_ptr[gidx] = beg + excl;  // covers row_ptr[N]=E too
    __syncthreads();
    s[t] = excl;  // becomes intra-bucket cursor
    __syncthreads();
    for (int j = beg + t; j < end; j += 512) {
        int2 rec = ebuf[j];
        int dlo = (rec.x >> 17) & (BN - 1);
        int g = batch[b * BN + dlo];  // L1-hot (1-2 lines per bucket)
        int r = atomicAdd(&s[dlo], 1);
        int2 o;
        o.x = (rec.x & 0x1FFFF) | (g << 17);  // src | graph<<17
        o.y = rec.y;                          // weight bits
        csr[beg + r] = o;
    }
}

// ---- kernel 3: fused gather + MFMA dense -----------------------------------
// One wave per 16-node tile. Phase 1: 16 lane-groups of 4 lanes, one node per
// group, one int4 (16 fp8 features) per lane; fp8 row = 64B = 1 line/edge.
// Unroll-4; invalid slots clamp to j (the line already in flight this
// iteration -> MSHR-merge, NO extra fetch; weight 0 kills the contribution).
// Rows land in the per-wave LDS tile as bf16 (stride 72 shorts). Phase 2:
// inline MFMA with hi/lo-split weights (A-root from bf16 xh); epilogue writes
// dense p[] and q[] (coalesced f32x4 stores -- no atomics).
__global__ __launch_bounds__(256) void gather_dense_kernel(
    const unsigned char* __restrict__ xf8, const unsigned short* __restrict__ xh,
    const int* __restrict__ row_ptr, const int2* __restrict__ csr,
    const unsigned short* __restrict__ whirel,
    const unsigned short* __restrict__ wlorel,
    const unsigned short* __restrict__ whiroot,
    const unsigned short* __restrict__ wloroot,
    const float* __restrict__ b1rel, const float* __restrict__ u,
    const float* __restrict__ v, float* __restrict__ p, float* __restrict__ q,
    int ntiles) {
    __shared__ unsigned short arow[4][16 * AST];  // 4 waves x 2304B = 9216B
    int lane = threadIdx.x & 63;
    int wv = threadIdx.x >> 6;
    int wave = (blockIdx.x << 2) + wv;
    if (wave >= ntiles) return;  // whole-wave exit; no block barriers used
    unsigned short* my = &arow[wv][0];
    int nb = wave * 16;

    // ---- phase 1: gather 16 node rows into LDS (fp8, 1 line/edge) ----
    {
        int g4 = lane >> 2;  // node 0..15
        int c4 = lane & 3;   // 16-feature chunk
        int node = nb + g4;
        int beg = row_ptr[node], end = row_ptr[node + 1];
        float a[16];
#pragma unroll
        for (int t = 0; t < 16; ++t) a[t] = 0.f;
        const unsigned char* xb = xf8 + (size_t)c4 * 16;
        for (int j = beg; j < end; j += 4) {
            // invalid slots alias edge j: same cache line already in flight
            // (MSHR-merge, no extra fetch), contribution killed by w=0.
            int i1 = (j + 1 < end) ? j + 1 : j;
            int i2 = (j + 2 < end) ? j + 2 : j;
            int i3 = (j + 3 < end) ? j + 3 : j;
            int2 e0 = csr[j];
            int2 e1 = csr[i1];
            int2 e2 = csr[i2];
            int2 e3 = csr[i3];
            int4 r0 = *(const int4*)(xb + (size_t)(e0.x & 0x1FFFF) * 64);
            int4 r1 = *(const int4*)(xb + (size_t)(e1.x & 0x1FFFF) * 64);
            int4 r2 = *(const int4*)(xb + (size_t)(e2.x & 0x1FFFF) * 64);
            int4 r3 = *(const int4*)(xb + (size_t)(e3.x & 0x1FFFF) * 64);
            float w0 = __int_as_float(e0.y);
            float w1 = (j + 1 < end) ? __int_as_float(e1.y) : 0.f;
            float w2 = (j + 2 < end) ? __int_as_float(e2.y) : 0.f;
            float w3 = (j + 3 < end) ? __int_as_float(e3.y) : 0.f;
            fma4(r0.x, w0, a + 0);
            fma4(r0.y, w0, a + 4);
            fma4(r0.z, w0, a + 8);
            fma4(r0.w, w0, a + 12);
            fma4(r1.x, w1, a + 0);
            fma4(r1.y, w1, a + 4);
            fma4(r1.z, w1, a + 8);
            fma4(r1.w, w1, a + 12);
            fma4(r2.x, w2, a + 0);
            fma4(r2.y, w2, a + 4);
            fma4(r2.z, w2, a + 8);
            fma4(r2.w, w2, a + 12);
            fma4(r3.x, w3, a + 0);
            fma4(r3.y, w3, a + 4);
            fma4(r3.z, w3, a + 8);
            fma4(r3.w, w3, a + 12);
        }
        u16x8 o0, o1;
#pragma unroll
        for (int t = 0; t < 8; ++t) {
            o0[t] = f2bf(a[t]);
            o1[t] = f2bf(a[8 + t]);
        }
        *(u16x8*)(my + g4 * AST + c4 * 16) = o0;
        *(u16x8*)(my + g4 * AST + c4 * 16 + 8) = o1;
    }

    // ---- phase 2: MFMA dense on the 16-node tile ----
    int lo4 = lane & 15;
    int quad = lane >> 4;
    f32x4 acc4[4];
#pragma unroll
    for (int t = 0; t < 4; ++t) acc4[t] = (f32x4){0.f, 0.f, 0.f, 0.f};
#pragma unroll
    for (int s = 0; s < 2; ++s) {  // K-step: f in [s*32, s*32+32)
        bf16x8 Aa = *(const bf16x8*)(my + lo4 * AST + s * 32 + quad * 8);
        bf16x8 Ax = *(const bf16x8*)(xh + (size_t)(nb + lo4) * 64 + s * 32 +
                                     quad * 8);
#pragma unroll
        for (int t = 0; t < 4; ++t) {  // h-tile: h in [t*16, t*16+16)
            int off = (t * 16 + lo4) * 64 + s * 32 + quad * 8;
            bf16x8 bhr = *(const bf16x8*)(whirel + off);
            bf16x8 blr = *(const bf16x8*)(wlorel + off);
            bf16x8 bhx = *(const bf16x8*)(whiroot + off);
            bf16x8 blx = *(const bf16x8*)(wloroot + off);
            acc4[t] = __builtin_amdgcn_mfma_f32_16x16x32_bf16(Aa, bhr, acc4[t],
                                                              0, 0, 0);
            acc4[t] = __builtin_amdgcn_mfma_f32_16x16x32_bf16(Aa, blr, acc4[t],
                                                              0, 0, 0);
            acc4[t] = __builtin_amdgcn_mfma_f32_16x16x32_bf16(Ax, bhx, acc4[t],
                                                              0, 0, 0);
            acc4[t] = __builtin_amdgcn_mfma_f32_16x16x32_bf16(Ax, blx, acc4[t],
                                                              0, 0, 0);
        }
    }

    float pc[4] = {0.f, 0.f, 0.f, 0.f};
    float qc[4] = {0.f, 0.f, 0.f, 0.f};
#pragma unroll
    for (int t = 0; t < 4; ++t) {
        float bb = b1rel[t * 16 + lo4];
        float uu = u[t * 16 + lo4];
        float vv = v[t * 16 + lo4];
#pragma unroll
        for (int r = 0; r < 4; ++r) {
            float h1 = fmaxf(acc4[t][r] + bb, 0.f);
            pc[r] += uu * h1;
            qc[r] += vv * h1;
        }
    }
#pragma unroll
    for (int off = 1; off < 16; off <<= 1) {
#pragma unroll
        for (int r = 0; r < 4; ++r) {
            pc[r] += __shfl_xor(pc[r], off);
            qc[r] += __shfl_xor(qc[r], off);
        }
    }
    if (lo4 == 0) {  // lanes 0,16,32,48: nodes nb+quad*4 .. +3
        f32x4 po = {pc[0], pc[1], pc[2], pc[3]};
        f32x4 qo = {qc[0], qc[1], qc[2], qc[3]};
        *(f32x4*)(p + nb + quad * 4) = po;
        *(f32x4*)(q + nb + quad * 4) = qo;
    }
}

// ---- kernel 4: fused pooling + last-block epilogue -------------------------
// blocks [0, PT_NB): T_g edge-flat over csr (graph id in csr.x bits 17-23,
// monotone -> curg accumulate + LDS flush). blocks [PT_NB, PT_NB+PS_NB):
// S_g node-flat (counts already in gc from prep). Last block to finish
// (done-counter) computes out[].
#define PT_EPT 8
#define PT_EPW (64 * PT_EPT)   // 512 edges per wave
#define PT_NB ((N_EDGES + 4 * PT_EPW - 1) / (4 * PT_EPW))  // 489
#define PS_NB 98
__global__ __launch_bounds__(256) void pool_both(
    const int2* __restrict__ csr, const float* __restrict__ p,
    const float* __restrict__ q, const int* __restrict__ batch,
    float* __restrict__ gp, float* __restrict__ gq,
    const float* __restrict__ gc, int* __restrict__ done,
    const float* __restrict__ C, float* __restrict__ out, int E, int N) {
    __shared__ float lbuf[NGRAPHS];
    __shared__ int amLast;
    int tid = threadIdx.x;
    if (tid < NGRAPHS) lbuf[tid] = 0.f;
    __syncthreads();
    if (blockIdx.x < PT_NB) {
        int lane = tid & 63;
        int wid = (blockIdx.x * 256 + tid) >> 6;
        int base = wid * PT_EPW;
        float acc = 0.f;
        int curg = -1;
#pragma unroll
        for (int i = 0; i < PT_EPT; ++i) {
            int j = base + i * 64 + lane;
            if (j < E) {
                int2 e = csr[j];
                int g = ((unsigned)e.x) >> 17;
                float val = __int_as_float(e.y) * p[e.x & 0x1FFFF];
                if (g != curg) {
                    if (curg >= 0) atomicAdd(&lbuf[curg], acc);
                    curg = g;
                    acc = 0.f;
                }
                acc += val;
            }
        }
        if (curg >= 0) atomicAdd(&lbuf[curg], acc);
        __syncthreads();
        if (tid < NGRAPHS) {
            float t = lbuf[tid];
            if (t != 0.f) atomicAdd(&gp[tid], t);
        }
    } else {
        int bid = blockIdx.x - PT_NB;
        for (int i = bid * 256 + tid; i < N; i += PS_NB * 256) {
            atomicAdd(&lbuf[batch[i]], q[i]);
        }
        __syncthreads();
        if (tid < NGRAPHS) {
            float t = lbuf[tid];
            if (t != 0.f) atomicAdd(&gq[tid], t);
        }
    }
    // ---- last-block epilogue ----
    __syncthreads();
    if (tid == 0) {
        __threadfence();  // make this block's atomics visible device-wide
        amLast = (atomicAdd(done, 1) == PT_NB + PS_NB - 1);
    }
    __syncthreads();
    if (amLast) {
        __threadfence();
        if (tid < NGRAPHS) {
            // coherent read-back of device-scope accumulators
            float pv = atomicAdd(&gp[tid], 0.f);
            float qv = atomicAdd(&gq[tid], 0.f);
            float cv = atomicAdd((float*)&gc[tid], 0.f);
            out[tid] = (pv + qv) / fmaxf(cv, 1.f) + C[0];
        }
    }
}

extern "C" void kernel_launch(void* const* d_in, const int* in_sizes, int n_in,
                              void* d_out, int out_size, void* d_ws,
                              size_t ws_size, hipStream_t stream) {
    const float* x      = (const float*)d_in[0];   // [N,64]
    const int*   ei     = (const int*)d_in[1];     // [2,E]
    const float* ew     = (const float*)d_in[2];   // [E]
    const int*   batch  = (const int*)d_in[3];     // [N] sorted
    const float* w1rel  = (const float*)d_in[4];
    const float* b1rel  = (const float*)d_in[5];
    const float* w1root = (const float*)d_in[6];
    const float* w2rel  = (const float*)d_in[7];
    const float* b2rel  = (const float*)d_in[8];
    const float* w2root = (const float*)d_in[9];
    const float* wlin   = (const float*)d_in[10];
    const float* blin   = (const float*)d_in[11];
    float* out = (float*)d_out;

    // ---- workspace layout ----
    // csr [0,8M) | ebuf [8M,16M) | weights/p/q/misc | row_ptr | xh | xf8.
    char* wsb = (char*)d_ws;
    int2* csr  = (int2*)wsb;                                   // 8 MB
    int2* ebuf = (int2*)(wsb + (size_t)N_EDGES * 8);           // 8 MB
    char* tail = wsb + (size_t)N_EDGES * 16;
    unsigned short* whirel  = (unsigned short*)tail;
    unsigned short* wlorel  = whirel + 4096;
    unsigned short* whiroot = wlorel + 4096;
    unsigned short* wloroot = whiroot + 4096;
    float* p  = (float*)(wloroot + 4096);                      // N
    float* q  = p + N_NODES;                                   // N
    float* u  = q + N_NODES;                                   // 64
    float* v  = u + 64;                                        // 64
    float* C  = v + 64;                                        // 1
    int*   bcount = (int*)(C + 1);                             // NBUCK
    float* gp = (float*)(bcount + NBUCK);                      // 128
    float* gq = gp + NGRAPHS;                                  // 128
    float* gc = gq + NGRAPHS;                                  // 128
    int*   done   = (int*)(gc + NGRAPHS);                      // 1
    int*   cursor = done + 1;                                  // NBUCK
    int*   row_ptr = cursor + NBUCK;                           // N+1
    unsigned short* xh = (unsigned short*)(row_ptr + N_NODES + 2);  // N*64
    int*   xf8 = (int*)(xh + (size_t)N_NODES * 64);            // N*64 bytes

    // zero: bcount, gp, gq, gc, done, cursor (contiguous)
    hipMemsetAsync(bcount, 0, (2 * NBUCK + 3 * NGRAPHS + 1) * sizeof(int),
                   stream);

    prep_all_kernel<<<PREP_TOTAL, 256, 0, stream>>>(
        x, xh, xf8, w1rel, w1root, w2rel, w2root, wlin, b2rel, blin, whirel,
        wlorel, whiroot, wloroot, u, v, C, ei, bcount, batch, gc, N_EDGES);

    bucket_fill<<<FILL_NB, 256, 0, stream>>>(ei, ew, bcount, cursor, ebuf,
                                             N_EDGES);
    csr_build<<<NBUCK, 512, 0, stream>>>(bcount, ebuf, batch, row_ptr, csr,
                                         N_NODES);

    gather_dense_kernel<<<(NTILES + 3) / 4, 256, 0, stream>>>(
        (const unsigned char*)xf8, xh, row_ptr, csr, whirel, wlorel, whiroot,
        wloroot, b1rel, u, v, p, q, NTILES);

    pool_both<<<PT_NB + PS_NB, 256, 0, stream>>>(csr, p, q, batch, gp, gq, gc,
                                                 done, C, out, N_EDGES,
                                                 N_NODES);
}